// Round 1
// 143.073 us; speedup vs baseline: 1.0919x; 1.0919x over previous
//
#include <hip/hip_runtime.h>

// Problem constants (from reference)
#define ZD_ 64
#define PD_ 16
#define DH_ 128

// ---------------------------------------------------------------------------
// K0: hid[64][128] = relu([z_all | pde] @ W1^T + b1)   (unchanged, ~few µs)
// ---------------------------------------------------------------------------
__global__ void hid_kernel(const float* __restrict__ z_all,
                           const float* __restrict__ W1,
                           const float* __restrict__ b1,
                           const float* __restrict__ pde,
                           float* __restrict__ hid) {
    int gid = blockIdx.x * 256 + threadIdx.x;   // 8192 outputs
    int r = gid >> 7;                            // z row (0..63)
    int d = gid & 127;                           // hidden unit
    const float* w = W1 + d * (ZD_ + PD_);
    const float* z = z_all + r * ZD_;
    float acc = b1[d];
    #pragma unroll 8
    for (int c = 0; c < ZD_; ++c) acc += z[c] * w[c];
    #pragma unroll
    for (int c = 0; c < PD_; ++c) acc += pde[c] * w[ZD_ + c];
    hid[gid] = fmaxf(acc, 0.0f);
}

// ---------------------------------------------------------------------------
// K1 (fused exe + outer): block = (ob, ibg) with ibg a group of 4 ib values.
//
//   For this block: n0 = ob*576 + ibg*36; W2 rows n0..n0+35 (one contiguous
//   18.4 KB slab, read ONCE globally — rows partition exactly across blocks).
//   Thread t: cell = t>>2 (= hk = h*8+kb, 0..63), ib = t&3.
//   exe[o][i][k] = hid[cell] . W2[n0 + ib*9 + k] + b2[n0 + ib*9 + k]
//     with o = h*64+ob, i = kb*64 + ibg*4 + ib.
//   acc[9] kept in registers -> s_exe; unet gather staged in s_un; epilogue
//   writes 64 runs of 4*81 = 324 floats (1296 B, 16B-aligned since
//   i0 = kb*64+ibg*4 ≡ 0 mod 4) as fully-coalesced float4 stores.
//
//   LDS reads in the dot loop: only 4 distinct rows per wave (16-lane
//   broadcast); stride 132 spreads them over distinct bank groups ->
//   conflict-free. LDS total 37,440 B -> 4 blocks/CU; grid 1024 = one
//   resident round on 256 CUs.
// ---------------------------------------------------------------------------
__global__ __launch_bounds__(256, 4) void fused_kernel(
        const float* __restrict__ hid,
        const float* __restrict__ W2,
        const float* __restrict__ b2,
        const float* __restrict__ unet,
        float* __restrict__ out) {
    __shared__ __align__(16) float s_w2[36 * 132];   // 19,008 B
    __shared__ float s_exe[64 * 36];                 //  9,216 B  [cell][ib][k]
    __shared__ float s_un [64 * 36];                 //  9,216 B  [cell][ib][l]

    int tid = threadIdx.x;
    int b   = blockIdx.x;
    int ob  = b >> 4;            // 0..63
    int ibg = b & 15;            // 0..15
    int n0  = ob * 576 + ibg * 36;

    // --- Stage W2 slab: 36 rows x 128 floats = 1152 float4, contiguous ---
    const float4* g4 = reinterpret_cast<const float4*>(W2 + (size_t)n0 * DH_);
    for (int j = tid; j < 1152; j += 256) {
        int row  = j >> 5;                // 0..35
        int col4 = j & 31;                // float4 within row
        *reinterpret_cast<float4*>(&s_w2[row * 132 + col4 * 4]) = g4[j];
    }

    // --- Stage unet gather: 64 runs x 36 contiguous floats ---
    for (int idx = tid; idx < 2304; idx += 256) {    // exactly 9 iters
        int rr = idx / 36;                // run = cell (h*8+kb)
        int jj = idx - rr * 36;
        int h  = rr >> 3, kb = rr & 7;
        size_t ub = ((size_t)((h * 64 + ob) * 512 + kb * 64 + ibg * 4)) * 9;
        s_un[idx] = unet[ub + jj];
    }
    __syncthreads();

    // --- Per-thread: 9 dot products of length 128 ---
    int cell = tid >> 2;                  // 0..63
    int ib   = tid & 3;                   // 0..3
    const float4* h4p = reinterpret_cast<const float4*>(hid + cell * DH_);
    const float*  wb  = s_w2 + ib * 9 * 132;
    const float*  bp  = b2 + n0 + ib * 9;

    float acc[9];
    #pragma unroll
    for (int k = 0; k < 9; ++k) acc[k] = bp[k];

    #pragma unroll 4
    for (int c = 0; c < 32; ++c) {
        float4 h4 = h4p[c];               // 16 distinct 16B addrs/wave, L1/L2-hot
        #pragma unroll
        for (int k = 0; k < 9; ++k) {
            float4 w4 = *reinterpret_cast<const float4*>(wb + k * 132 + c * 4);
            acc[k] += h4.x * w4.x + h4.y * w4.y + h4.z * w4.z + h4.w * w4.w;
        }
    }
    #pragma unroll
    for (int k = 0; k < 9; ++k) s_exe[tid * 9 + k] = acc[k];   // = [cell][ib][k]
    __syncthreads();

    // --- Epilogue: outer product, 64 runs x 81 float4 (coalesced stores) ---
    for (int idx = tid; idx < 5184; idx += 256) {    // 20-21 iters
        int rr = idx / 81;                // run (= cell)
        int q  = idx - rr * 81;           // float4 within run
        float4 v;
        float* vp = &v.x;
        #pragma unroll
        for (int j2 = 0; j2 < 4; ++j2) {
            int e   = q * 4 + j2;         // float within run, 0..323
            int ibb = e / 81;
            int rem = e - ibb * 81;
            int k   = rem / 9;
            int l   = rem - k * 9;
            vp[j2] = s_exe[rr * 36 + ibb * 9 + k] * s_un[rr * 36 + ibb * 9 + l];
        }
        int h = rr >> 3, kb = rr & 7;
        size_t base = ((size_t)((h * 64 + ob) * 512 + kb * 64 + ibg * 4)) * 81;
        reinterpret_cast<float4*>(out + base)[q] = v;   // base ≡ 0 mod 16 B
    }
}

// ---------------------------------------------------------------------------
extern "C" void kernel_launch(void* const* d_in, const int* in_sizes, int n_in,
                              void* d_out, int out_size, void* d_ws, size_t ws_size,
                              hipStream_t stream) {
    const float* z_all = (const float*)d_in[0];  // [64,64]
    const float* W1    = (const float*)d_in[1];  // [128,80]
    const float* b1    = (const float*)d_in[2];  // [128]
    const float* W2    = (const float*)d_in[3];  // [36864,128]
    const float* b2    = (const float*)d_in[4];  // [36864]
    const float* unet  = (const float*)d_in[5];  // [512,512,9]
    const float* pde   = (const float*)d_in[6];  // [16]
    float* out = (float*)d_out;                  // [512,512,9,9]

    float* hid = (float*)d_ws;                   // 8192 floats (only ws use now)

    hid_kernel<<<32, 256, 0, stream>>>(z_all, W1, b1, pde, hid);
    fused_kernel<<<1024, 256, 0, stream>>>(hid, W2, b2, unet, out);
}